// Round 4
// baseline (1059.439 us; speedup 1.0000x reference)
//
#include <hip/hip_runtime.h>
#include <hip/hip_fp16.h>

#define EMB_D 64
#define SB 1024     // scan block size
#define SPAN 128    // nodes per group (pow2: group = dst>>7, local = dst&127)
#define MAXG 1024   // max groups for Tier A3 LDS arrays
#define MAXK 3072   // max (group,slice) keys for Tier A4 LDS arrays
#define NCHUNK2 512 // edge chunks
#define CHMAX 4096  // max edges per chunk for LDS record buffer (32 KB)
#define SLICE_SH 14 // src-slice shift: 16384 nodes = 2 MB of emb16 per slice
#define CAST_BLOCKS 256
#define PST 512     // partition_sortK threads

// ===========================================================================
// Tier A4: group-gather with LDS accumulators + src-slice L2 phasing.
//   A1 : fused fp16 cast + per-chunk (group,slice)-key histogram (LDS only)
//   scan: 3-phase over [NK][NCHUNK2], IN-PLACE (scanT aliases cntT)
//   PS : per-chunk LDS counting sort by key -> stream8 (group-major,
//        slice-minor within each group: all blocks sweep slices in step)
//   GG : block per group: stream segment coalesced, random row fetch,
//        LDS fp32 atomic accumulate into 128x64 tile, normalize, write.
//        No per-node CSR, no packed/offsets, no group_csr pass.
// Tier A3: LDS-sorted partition + CSR + gatherV (proven ~190 us).
// Tier A : one-global-atomic-pass pipeline (proven 270 us).
// Tier C : atomic scatter fallback.
// ===========================================================================

__device__ __forceinline__ float h15_to_float(unsigned int bits) {
    return __half2float(__ushort_as_half((unsigned short)bits));
}

// --- A4-1: fused cast + chunked (group,slice) histogram -------------------
__global__ void a1_cast_histK(const float2* __restrict__ embin,
                              __half2* __restrict__ emb16, int n2,
                              const int* __restrict__ src,
                              const int* __restrict__ dst,
                              int* __restrict__ cntT,   // [NK][NCHUNK2]
                              int E, int NK, int S, int chunk) {
    if (blockIdx.x < CAST_BLOCKS) {
        int i = blockIdx.x * blockDim.x + threadIdx.x;
        int st = CAST_BLOCKS * blockDim.x;
        for (; i < n2; i += st)
            emb16[i] = __float22half2_rn(embin[i]);
    } else {
        __shared__ int bins[MAXK];
        int hb = blockIdx.x - CAST_BLOCKS;
        for (int k = threadIdx.x; k < NK; k += blockDim.x) bins[k] = 0;
        __syncthreads();
        int beg = hb * chunk;
        int end = min(beg + chunk, E);
        for (int i = beg + threadIdx.x; i < end; i += blockDim.x) {
            int key = (dst[i] >> 7) * S + (src[i] >> SLICE_SH);
            atomicAdd(&bins[key], 1);
        }
        __syncthreads();
        for (int k = threadIdx.x; k < NK; k += blockDim.x)
            cntT[k * NCHUNK2 + hb] = bins[k];
    }
}

// --- A3-1: fused cast + chunked group histogram ---------------------------
__global__ void a1_cast_hist(const float2* __restrict__ embin,
                             __half2* __restrict__ emb16, int n2,
                             const int* __restrict__ dst,
                             int* __restrict__ cntT,   // [G][ncols]
                             int E, int G, int chunk, int ncols) {
    if (blockIdx.x < CAST_BLOCKS) {
        int i = blockIdx.x * blockDim.x + threadIdx.x;
        int st = CAST_BLOCKS * blockDim.x;
        for (; i < n2; i += st)
            emb16[i] = __float22half2_rn(embin[i]);
    } else {
        __shared__ int bins[MAXG];
        int hb = blockIdx.x - CAST_BLOCKS;
        for (int g = threadIdx.x; g < G; g += blockDim.x) bins[g] = 0;
        __syncthreads();
        int beg = hb * chunk;
        int end = min(beg + chunk, E);
        for (int i = beg + threadIdx.x; i < end; i += blockDim.x)
            atomicAdd(&bins[dst[i] >> 7], 1);
        __syncthreads();
        for (int g = threadIdx.x; g < G; g += blockDim.x)
            cntT[g * ncols + hb] = bins[g];
    }
}

// --- generic 3-phase exclusive scan ---------------------------------------
__global__ void scan_reduceB(const int* __restrict__ counts,
                             int* __restrict__ partial, int M) {
    __shared__ int wsum[16];
    const int tid = threadIdx.x, lane = tid & 63, wid = tid >> 6;
    int i = blockIdx.x * SB + tid;
    int v = (i < M) ? counts[i] : 0;
    #pragma unroll
    for (int off = 32; off > 0; off >>= 1)
        v += __shfl_xor(v, off, 64);
    if (lane == 0) wsum[wid] = v;
    __syncthreads();
    if (tid == 0) {
        int s = 0;
        #pragma unroll
        for (int k = 0; k < 16; ++k) s += wsum[k];
        partial[blockIdx.x] = s;
    }
}

// multi-pass: handles any numB (nPass sequential 1024-wide scans w/ carry)
__global__ void scan_partials(const int* __restrict__ partial,
                              int* __restrict__ blockoff,
                              int* __restrict__ offsets, int numB, int M) {
    __shared__ int wsum[16];
    __shared__ int wpre[16];
    __shared__ int carry;
    const int tid = threadIdx.x, lane = tid & 63, wid = tid >> 6;
    if (tid == 0) carry = 0;
    const int nPass = (numB + SB - 1) / SB;
    for (int p = 0; p < nPass; ++p) {
        __syncthreads();
        int base = carry;
        int idx = p * SB + tid;
        int v = (idx < numB) ? partial[idx] : 0;
        int x = v;
        #pragma unroll
        for (int off = 1; off < 64; off <<= 1) {
            int t = __shfl_up(x, off, 64);
            if (lane >= off) x += t;
        }
        if (lane == 63) wsum[wid] = x;
        __syncthreads();
        if (wid == 0) {
            int s = (lane < 16) ? wsum[lane] : 0;
            #pragma unroll
            for (int off = 1; off < 16; off <<= 1) {
                int t = __shfl_up(s, off, 64);
                if (lane >= off) s += t;
            }
            if (lane < 16) wpre[lane] = s;
        }
        __syncthreads();
        int excl = base + ((wid > 0) ? wpre[wid - 1] : 0) + (x - v);
        if (idx < numB) blockoff[idx] = excl;
        __syncthreads();
        if (tid == 0) carry = base + wpre[15];
    }
    __syncthreads();
    if (tid == 0) offsets[M] = carry;   // grand total = E
}

__global__ void scan_applyB(const int* __restrict__ counts,
                            const int* __restrict__ blockoff,
                            int* __restrict__ offsets, int M) {
    __shared__ int wsum[16];
    __shared__ int wpre[16];
    const int tid = threadIdx.x, lane = tid & 63, wid = tid >> 6;
    int i = blockIdx.x * SB + tid;
    int v = (i < M) ? counts[i] : 0;
    int x = v;
    #pragma unroll
    for (int off = 1; off < 64; off <<= 1) {
        int t = __shfl_up(x, off, 64);
        if (lane >= off) x += t;
    }
    if (lane == 63) wsum[wid] = x;
    __syncthreads();
    if (wid == 0) {
        int s = (lane < 16) ? wsum[lane] : 0;
        #pragma unroll
        for (int off = 1; off < 16; off <<= 1) {
            int t = __shfl_up(s, off, 64);
            if (lane >= off) s += t;
        }
        if (lane < 16) wpre[lane] = s;
    }
    __syncthreads();
    int excl = blockoff[blockIdx.x] + ((wid > 0) ? wpre[wid - 1] : 0) + (x - v);
    if (i < M) offsets[i] = excl;
}

// in-place variant: data[i] <- exclusive_scan(data)[i] (no aliasing UB)
__global__ void scan_apply_ip(int* __restrict__ data,
                              const int* __restrict__ blockoff, int M) {
    __shared__ int wsum[16];
    __shared__ int wpre[16];
    const int tid = threadIdx.x, lane = tid & 63, wid = tid >> 6;
    int i = blockIdx.x * SB + tid;
    int v = (i < M) ? data[i] : 0;
    int x = v;
    #pragma unroll
    for (int off = 1; off < 64; off <<= 1) {
        int t = __shfl_up(x, off, 64);
        if (lane >= off) x += t;
    }
    if (lane == 63) wsum[wid] = x;
    __syncthreads();
    if (wid == 0) {
        int s = (lane < 16) ? wsum[lane] : 0;
        #pragma unroll
        for (int off = 1; off < 16; off <<= 1) {
            int t = __shfl_up(s, off, 64);
            if (lane >= off) s += t;
        }
        if (lane < 16) wpre[lane] = s;
    }
    __syncthreads();
    int excl = blockoff[blockIdx.x] + ((wid > 0) ? wpre[wid - 1] : 0) + (x - v);
    if (i < M) data[i] = excl;
}

// --- A4-PS: per-chunk LDS counting sort by (group,slice) key --------------
__global__ __launch_bounds__(PST) void partition_sortK(
        const int* __restrict__ src,
        const int* __restrict__ dst,
        const float* __restrict__ w,
        const int* __restrict__ scanT,   // [NK*NCHUNK2+1] (scanned in place)
        uint2* __restrict__ stream8,     // [E]
        int E, int NK, int S, int chunk) {
    __shared__ uint2 recs[CHMAX];        // 32 KB
    __shared__ int cur[MAXK];            // 12 KB
    __shared__ int delta[MAXK];          // 12 KB
    __shared__ int wtot[8];
    const int tid = threadIdx.x, lane = tid & 63, wv = tid >> 6;
    const int b = blockIdx.x;
    const int beg = b * chunk;
    const int end = min(beg + chunk, E);
    const int n = end - beg;

    // phase 1: local histogram into cur
    for (int k = tid; k < NK; k += PST) cur[k] = 0;
    __syncthreads();
    for (int i = beg + tid; i < end; i += PST) {
        int key = (dst[i] >> 7) * S + (src[i] >> SLICE_SH);
        atomicAdd(&cur[key], 1);
    }
    __syncthreads();

    // phase 2: segment scan -> local bases; delta = global base - local base
    const int K = (NK + PST - 1) / PST;  // <= 6 (guard: NK <= MAXK)
    int vals[8];
    int acc = 0;
    #pragma unroll
    for (int k = 0; k < 8; ++k) {
        int key = tid * K + k;
        int c = (k < K && key < NK) ? cur[key] : 0;
        vals[k] = c;
        acc += c;
    }
    __syncthreads();                     // all cur reads done before overwrite
    int x = acc;
    #pragma unroll
    for (int off = 1; off < 64; off <<= 1) {
        int t = __shfl_up(x, off, 64);
        if (lane >= off) x += t;
    }
    if (lane == 63) wtot[wv] = x;
    __syncthreads();
    int woff = 0;
    #pragma unroll
    for (int k2 = 0; k2 < 8; ++k2)
        woff += (k2 < wv) ? wtot[k2] : 0;
    int run = woff + x - acc;
    #pragma unroll
    for (int k = 0; k < 8; ++k) {
        int key = tid * K + k;
        if (k < K && key < NK) {
            cur[key] = run;
            delta[key] = scanT[key * NCHUNK2 + b] - run;
            run += vals[k];
        }
    }
    __syncthreads();

    // phase 3: LDS scatter, key-sorted
    for (int i = beg + tid; i < end; i += PST) {
        int d = dst[i];
        int key = (d >> 7) * S + (src[i] >> SLICE_SH);
        unsigned int wb = __half_as_ushort(__float2half_rn(w[i]));
        unsigned int pk = ((unsigned int)src[i] << 15) | (wb & 0x7FFFu);
        int j = atomicAdd(&cur[key], 1);
        recs[j] = make_uint2(pk, (unsigned int)(d & (SPAN - 1)) |
                                 ((unsigned int)key << 7));
    }
    __syncthreads();

    // phase 4: linear coalesced drain
    for (int j = tid; j < n; j += PST) {
        uint2 r = recs[j];
        int key = (int)(r.y >> 7);
        stream8[delta[key] + j] = make_uint2(r.x, r.y & (SPAN - 1u));
    }
}

// --- A4-GG: per-group gather with LDS fp32 accumulators -------------------
// Block g: nodes [g*SPAN, g*SPAN+128). Streams its stream8 segment (slice-
// ordered -> whole GPU sweeps 2MB src-slices in phase => L2-resident rows).
// acc layout rotated: dim d of node dl stored at acc[dl*64 + ((d+dl)&63)].
__global__ __launch_bounds__(512) void gather_group(
        const char* __restrict__ emb16b,      // row v at byte v*128
        const uint2* __restrict__ stream8,    // [E] {pk, dl}
        const int* __restrict__ scanT,
        float* __restrict__ out, int N, int SN) {
    __shared__ float acc[SPAN * EMB_D];       // 32 KB
    const int g = blockIdx.x;
    const int tid = threadIdx.x;
    for (int i = tid; i < SPAN * EMB_D; i += 512) acc[i] = 0.f;
    const int base = scanT[(size_t)g * SN];
    const int endE = scanT[(size_t)(g + 1) * SN];
    __syncthreads();

    const int crew = tid >> 3;                // 64 record streams
    const int cl   = tid & 7;                 // 16B segment of 128B row
    const unsigned qlo = (unsigned)(cl << 4);
    const int d0 = cl << 3;

    int i0 = base + crew;
    uint2 rec0 = (i0 < endE) ? stream8[i0] : make_uint2(0u, 0u);
    uint4 r0 = *reinterpret_cast<const uint4*>(
        emb16b + ((size_t)(rec0.x >> 15) * 128u + qlo));

    for (int i = i0; i < endE; i += 64) {
        int i1 = i + 64;
        uint2 rec1 = (i1 < endE) ? stream8[i1] : make_uint2(0u, 0u);
        uint4 r1 = *reinterpret_cast<const uint4*>(
            emb16b + ((size_t)(rec1.x >> 15) * 128u + qlo));   // next in flight

        float wt = h15_to_float(rec0.x & 0x7FFFu);
        int dl = (int)rec0.y;
        float* arow = acc + dl * EMB_D;
        int rot = d0 + dl;
        float2 x01 = __half22float2(*reinterpret_cast<__half2*>(&r0.x));
        float2 x23 = __half22float2(*reinterpret_cast<__half2*>(&r0.y));
        float2 x45 = __half22float2(*reinterpret_cast<__half2*>(&r0.z));
        float2 x67 = __half22float2(*reinterpret_cast<__half2*>(&r0.w));
        atomicAdd(&arow[(rot + 0) & 63], x01.x * wt);
        atomicAdd(&arow[(rot + 1) & 63], x01.y * wt);
        atomicAdd(&arow[(rot + 2) & 63], x23.x * wt);
        atomicAdd(&arow[(rot + 3) & 63], x23.y * wt);
        atomicAdd(&arow[(rot + 4) & 63], x45.x * wt);
        atomicAdd(&arow[(rot + 5) & 63], x45.y * wt);
        atomicAdd(&arow[(rot + 6) & 63], x67.x * wt);
        atomicAdd(&arow[(rot + 7) & 63], x67.y * wt);

        rec0 = rec1; r0 = r1;
    }
    __syncthreads();

    // normalize + write: 8 waves x 16 nodes
    const int lane = tid & 63, wv = tid >> 6;
    for (int nn = wv * 16; nn < wv * 16 + 16; ++nn) {
        int node = g * SPAN + nn;
        if (node >= N) break;
        float xv = acc[nn * EMB_D + ((lane + nn) & 63)];
        float ss = xv * xv;
        #pragma unroll
        for (int off = 32; off > 0; off >>= 1)
            ss += __shfl_xor(ss, off, 64);
        float scale = 1.0f / fmaxf(sqrtf(ss), 1e-12f);
        out[(size_t)node * EMB_D + lane] = xv * scale;
    }
}

// ===========================================================================
// Tier A3 kernels (proven ~190 us path)
// ===========================================================================
__global__ __launch_bounds__(256) void partition_sort(
        const int* __restrict__ src,
        const int* __restrict__ dst,
        const float* __restrict__ w,
        const int* __restrict__ cntT,    // [G][NCHUNK2]
        const int* __restrict__ scanT,   // [G*NCHUNK2+1]
        uint2* __restrict__ stream8,     // [E]
        int E, int G, int chunk) {
    __shared__ uint2 recs[CHMAX];
    __shared__ int cur[MAXG];
    __shared__ int delta[MAXG];
    __shared__ int wtot[4];

    const int tid = threadIdx.x, lane = tid & 63, wv = tid >> 6;
    const int b = blockIdx.x;
    const int beg = b * chunk;
    const int end = min(beg + chunk, E);
    const int n = end - beg;

    const int K = (G + 255) >> 8;
    int vals[4];
    int acc = 0;
    #pragma unroll
    for (int k = 0; k < 4; ++k) {
        int g = tid * K + k;
        int c = (k < K && g < G) ? cntT[g * NCHUNK2 + b] : 0;
        vals[k] = c;
        acc += c;
    }
    int x = acc;
    #pragma unroll
    for (int off = 1; off < 64; off <<= 1) {
        int t = __shfl_up(x, off, 64);
        if (lane >= off) x += t;
    }
    if (lane == 63) wtot[wv] = x;
    __syncthreads();
    int woff = 0;
    #pragma unroll
    for (int k2 = 0; k2 < 4; ++k2)
        woff += (k2 < wv) ? wtot[k2] : 0;
    int run = woff + x - acc;
    #pragma unroll
    for (int k = 0; k < 4; ++k) {
        int g = tid * K + k;
        if (k < K && g < G) {
            cur[g] = run;
            delta[g] = scanT[g * NCHUNK2 + b] - run;
            run += vals[k];
        }
    }
    __syncthreads();

    for (int i = beg + tid; i < end; i += blockDim.x) {
        int d = dst[i];
        unsigned int wb = __half_as_ushort(__float2half_rn(w[i]));
        unsigned int pk = ((unsigned int)src[i] << 15) | (wb & 0x7FFFu);
        int g = d >> 7;
        int j = atomicAdd(&cur[g], 1);
        recs[j] = make_uint2(pk, (unsigned int)(d & (SPAN - 1)) |
                                 ((unsigned int)g << 7));
    }
    __syncthreads();

    for (int j = tid; j < n; j += blockDim.x) {
        uint2 r = recs[j];
        int g = (int)(r.y >> 7);
        stream8[delta[g] + j] = make_uint2(r.x, r.y & (SPAN - 1u));
    }
}

__global__ void group_csr2(const uint2* __restrict__ stream8,
                           const int* __restrict__ scanT,
                           unsigned int* __restrict__ packed,
                           int* __restrict__ offsets, int N, int E) {
    __shared__ int hcnt[SPAN];
    __shared__ int cur[SPAN];
    __shared__ int wtot[4];
    int g = blockIdx.x;
    int tid = threadIdx.x;
    int base = scanT[g * NCHUNK2];
    int endE = scanT[(g + 1) * NCHUNK2];
    if (tid < SPAN) hcnt[tid] = 0;
    __syncthreads();
    for (int i = base + tid; i < endE; i += blockDim.x)
        atomicAdd(&hcnt[stream8[i].y], 1);
    __syncthreads();
    int v = (tid < SPAN) ? hcnt[tid] : 0;
    int lane = tid & 63, wv = tid >> 6;
    int x = v;
    #pragma unroll
    for (int off = 1; off < 64; off <<= 1) {
        int t = __shfl_up(x, off, 64);
        if (lane >= off) x += t;
    }
    if (lane == 63) wtot[wv] = x;
    __syncthreads();
    if (tid < SPAN) {
        int excl = x - v + ((wv == 1) ? wtot[0] : 0);
        cur[tid] = base + excl;
        int node = g * SPAN + tid;
        if (node < N) offsets[node] = base + excl;
    }
    if (g == 0 && tid == 0) offsets[N] = E;
    __syncthreads();
    for (int i = base + tid; i < endE; i += blockDim.x) {
        uint2 r = stream8[i];
        int slot = atomicAdd(&cur[r.y], 1);
        packed[slot] = r.x;
    }
}

// --- Tier A: fused cast + histogram-with-ranks ----------------------------
__global__ void p1_cast_hist_ranks(const float2* __restrict__ embin,
                                   __half2* __restrict__ emb16, int n2,
                                   const int* __restrict__ dst,
                                   int* __restrict__ counts,
                                   unsigned short* __restrict__ ranks,
                                   int E) {
    if (blockIdx.x < CAST_BLOCKS) {
        int i = blockIdx.x * blockDim.x + threadIdx.x;
        int st = CAST_BLOCKS * blockDim.x;
        for (; i < n2; i += st)
            emb16[i] = __float22half2_rn(embin[i]);
    } else {
        int i = (blockIdx.x - CAST_BLOCKS) * blockDim.x + threadIdx.x;
        int st = (gridDim.x - CAST_BLOCKS) * blockDim.x;
        for (; i < E; i += st)
            ranks[i] = (unsigned short)atomicAdd(&counts[dst[i]], 1);
    }
}

__global__ void bucketR_kernel(const int* __restrict__ src,
                               const int* __restrict__ dst,
                               const float* __restrict__ w,
                               const unsigned short* __restrict__ ranks,
                               const int* __restrict__ offsets,
                               unsigned int* __restrict__ packed,
                               int E, int span, int N) {
    int g = blockIdx.x & 7;
    int b = blockIdx.x >> 3;
    int lo = g * span;
    int hi = min(lo + span, N);
    int stride = (gridDim.x >> 3) * blockDim.x;
    for (int i = b * blockDim.x + threadIdx.x; i < E; i += stride) {
        int v = dst[i];
        if (v >= lo && v < hi) {
            unsigned int wb = __half_as_ushort(__float2half_rn(w[i]));
            packed[offsets[v] + (int)ranks[i]] =
                ((unsigned int)src[i] << 15) | (wb & 0x7FFFu);
        }
    }
}

// --- gatherV: eighth-wave per edge (used by Tier A3 / A) ------------------
__global__ __launch_bounds__(256) void gatherV_kernel(
        const char* __restrict__ emb16b,
        const int* __restrict__ offsets,
        const unsigned int* __restrict__ packed,
        float* __restrict__ out, int N) {
    int node = blockIdx.x * 4 + (threadIdx.x >> 6);
    int lane = threadIdx.x & 63;
    if (node >= N) return;
    int q  = lane >> 3;
    int ql = lane & 7;
    const unsigned qlo = (unsigned)(ql << 4);

    int beg = offsets[node];
    int end = offsets[node + 1];

    float a0=0.f,a1=0.f,a2=0.f,a3=0.f,a4=0.f,a5=0.f,a6=0.f,a7=0.f;

    int idx0 = beg + q;
    int idx1 = idx0 + 8;
    int idx2 = idx1 + 8;
    unsigned int pk0 = (idx0 < end) ? packed[idx0] : 0u;
    unsigned int pk1 = (idx1 < end) ? packed[idx1] : 0u;
    unsigned int pk2 = (idx2 < end) ? packed[idx2] : 0u;
    uint4 r0 = *reinterpret_cast<const uint4*>(emb16b + ((pk0 >> 15) * 128u + qlo));
    uint4 r1 = *reinterpret_cast<const uint4*>(emb16b + ((pk1 >> 15) * 128u + qlo));

    for (int j = beg; j < end; j += 8) {
        uint4 r2 = *reinterpret_cast<const uint4*>(
            emb16b + ((pk2 >> 15) * 128u + qlo));
        int idx3 = idx2 + 8;
        unsigned int pk3 = (idx3 < end) ? packed[idx3] : 0u;

        float wt = h15_to_float(pk0 & 0x7FFFu);
        float2 x01 = __half22float2(*reinterpret_cast<__half2*>(&r0.x));
        float2 x23 = __half22float2(*reinterpret_cast<__half2*>(&r0.y));
        float2 x45 = __half22float2(*reinterpret_cast<__half2*>(&r0.z));
        float2 x67 = __half22float2(*reinterpret_cast<__half2*>(&r0.w));
        a0 = fmaf(x01.x, wt, a0);
        a1 = fmaf(x01.y, wt, a1);
        a2 = fmaf(x23.x, wt, a2);
        a3 = fmaf(x23.y, wt, a3);
        a4 = fmaf(x45.x, wt, a4);
        a5 = fmaf(x45.y, wt, a5);
        a6 = fmaf(x67.x, wt, a6);
        a7 = fmaf(x67.y, wt, a7);

        pk0 = pk1; pk1 = pk2; pk2 = pk3;
        r0 = r1; r1 = r2;
        idx2 = idx3;
    }

    #pragma unroll
    for (int off = 8; off < 64; off <<= 1) {
        a0 += __shfl_xor(a0, off, 64);
        a1 += __shfl_xor(a1, off, 64);
        a2 += __shfl_xor(a2, off, 64);
        a3 += __shfl_xor(a3, off, 64);
        a4 += __shfl_xor(a4, off, 64);
        a5 += __shfl_xor(a5, off, 64);
        a6 += __shfl_xor(a6, off, 64);
        a7 += __shfl_xor(a7, off, 64);
    }
    float ss = a0*a0 + a1*a1 + a2*a2 + a3*a3 + a4*a4 + a5*a5 + a6*a6 + a7*a7;
    ss += __shfl_xor(ss, 1, 64);
    ss += __shfl_xor(ss, 2, 64);
    ss += __shfl_xor(ss, 4, 64);
    float scale = 1.0f / fmaxf(sqrtf(ss), 1e-12f);

    if (q == 0) {
        float4* po = reinterpret_cast<float4*>(out + (size_t)node * EMB_D
                                               + (ql << 3));
        po[0] = make_float4(a0 * scale, a1 * scale, a2 * scale, a3 * scale);
        po[1] = make_float4(a4 * scale, a5 * scale, a6 * scale, a7 * scale);
    }
}

// ===========================================================================
// Tier C: atomic scatter fallback.
// ===========================================================================
__global__ void lightgcn_scatter(const float* __restrict__ emb,
                                 const float* __restrict__ w,
                                 const int* __restrict__ src,
                                 const int* __restrict__ dst,
                                 float* __restrict__ h, int E) {
    long long t = (long long)blockIdx.x * blockDim.x + threadIdx.x;
    int e = (int)(t >> 4);
    int d = (int)(t & 15) << 2;
    if (e >= E) return;
    int s = src[e]; int v = dst[e]; float wt = w[e];
    const float4 m = *reinterpret_cast<const float4*>(emb + (size_t)s * EMB_D + d);
    float* o = h + (size_t)v * EMB_D + d;
    unsafeAtomicAdd(o + 0, m.x * wt);
    unsafeAtomicAdd(o + 1, m.y * wt);
    unsafeAtomicAdd(o + 2, m.z * wt);
    unsafeAtomicAdd(o + 3, m.w * wt);
}

__global__ void lightgcn_normalize(float* __restrict__ h, int N) {
    int row = blockIdx.x * (blockDim.x >> 6) + (threadIdx.x >> 6);
    int lane = threadIdx.x & 63;
    if (row >= N) return;
    float x = h[(size_t)row * EMB_D + lane];
    float ss = x * x;
    #pragma unroll
    for (int off = 32; off > 0; off >>= 1)
        ss += __shfl_xor(ss, off, 64);
    h[(size_t)row * EMB_D + lane] = x / fmaxf(sqrtf(ss), 1e-12f);
}

extern "C" void kernel_launch(void* const* d_in, const int* in_sizes, int n_in,
                              void* d_out, int out_size, void* d_ws, size_t ws_size,
                              hipStream_t stream) {
    const float* emb = (const float*)d_in[0];   // [N, 64] fp32
    const float* w   = (const float*)d_in[1];   // [E] fp32
    const int*   src = (const int*)d_in[2];     // [E] int32
    const int*   dst = (const int*)d_in[3];     // [E] int32
    float* out = (float*)d_out;

    const int N = in_sizes[0] / EMB_D;
    const int E = in_sizes[1];
    const int block = 256;
    const int numB = (N + SB - 1) / SB;
    const int G = (N + SPAN - 1) / SPAN;

    // ---- Tier A4 workspace: cnt/scanT[M4+1] | partial | blockoff |
    //      stream8[E] uint2 | emb16  (~30.8 MB) ----
    const int S4 = (N + (1 << SLICE_SH) - 1) >> SLICE_SH;
    const int NK4 = G * S4;
    const int M4 = NK4 * NCHUNK2;
    const int numB4 = (M4 + SB - 1) / SB;
    const int chunk4 = (E + NCHUNK2 - 1) / NCHUNK2;
    const int SN4 = S4 * NCHUNK2;
    size_t intsA4 = (size_t)(M4 + 1) + 2 * (size_t)numB4;
    size_t strOff4 = (intsA4 * sizeof(int) + 15) & ~(size_t)15;
    size_t embOff4 = (strOff4 + (size_t)E * sizeof(uint2) + 15) & ~(size_t)15;
    size_t neededA4 = embOff4 + (size_t)N * EMB_D * sizeof(__half);

    // ---- Tier A3 workspace (~35.7 MB) ----
    const int M3 = G * NCHUNK2;
    const int numB3 = (M3 + SB - 1) / SB;
    const int chunk3 = (E + NCHUNK2 - 1) / NCHUNK2;
    size_t intsA3 = (size_t)M3 + (size_t)(M3 + 1) + 2 * (size_t)numB3
                  + (size_t)(N + 1);
    size_t strOff = (intsA3 * sizeof(int) + 15) & ~(size_t)15;
    size_t pkdOff = strOff + (size_t)E * sizeof(uint2);
    size_t embOff3 = (pkdOff + (size_t)E * sizeof(unsigned int) + 15)
                     & ~(size_t)15;
    size_t neededA3 = embOff3 + (size_t)N * EMB_D * sizeof(__half);

    // ---- Tier A workspace (~21.7 MB) ----
    size_t intsA = (size_t)(2 * N + 1 + 2 * numB) + E;
    size_t ranksOff = intsA * sizeof(int);
    size_t embOffA = (ranksOff + (size_t)E * sizeof(unsigned short) + 15)
                     & ~(size_t)15;
    size_t neededA = embOffA + (size_t)N * EMB_D * sizeof(__half);

    if (ws_size >= neededA4 && NK4 <= MAXK && chunk4 <= CHMAX &&
        E < (1 << 28) && N < (1 << 17)) {
        int* cntT     = (int*)d_ws;              // M4+1 (becomes scanT)
        int* partial  = cntT + M4 + 1;           // numB4
        int* blockoff = partial + numB4;         // numB4
        uint2* stream8 = (uint2*)((char*)d_ws + strOff4);   // E
        __half2* emb16 = (__half2*)((char*)d_ws + embOff4);

        int n2 = N * (EMB_D / 2);

        a1_cast_histK<<<CAST_BLOCKS + NCHUNK2, block, 0, stream>>>(
            (const float2*)emb, emb16, n2, src, dst, cntT, E, NK4, S4, chunk4);

        scan_reduceB<<<numB4, SB, 0, stream>>>(cntT, partial, M4);
        scan_partials<<<1, SB, 0, stream>>>(partial, blockoff, cntT, numB4, M4);
        scan_apply_ip<<<numB4, SB, 0, stream>>>(cntT, blockoff, M4);

        partition_sortK<<<NCHUNK2, PST, 0, stream>>>(src, dst, w, cntT,
                                                     stream8, E, NK4, S4,
                                                     chunk4);
        gather_group<<<G, 512, 0, stream>>>((const char*)emb16, stream8, cntT,
                                            out, N, SN4);
    } else if (ws_size >= neededA3 && G <= MAXG && numB3 <= 2048 &&
               chunk3 <= CHMAX && E < (1 << 28)) {
        int* cntT     = (int*)d_ws;              // G*NCHUNK2
        int* scanT    = cntT + M3;               // G*NCHUNK2+1
        int* partial  = scanT + M3 + 1;          // numB3
        int* blockoff = partial + numB3;         // numB3
        int* offsets  = blockoff + numB3;        // N+1
        uint2* stream8 = (uint2*)((char*)d_ws + strOff);                // E
        unsigned int* packed = (unsigned int*)((char*)d_ws + pkdOff);   // E
        __half2* emb16 = (__half2*)((char*)d_ws + embOff3);

        int n2 = N * (EMB_D / 2);

        a1_cast_hist<<<CAST_BLOCKS + NCHUNK2, block, 0, stream>>>(
            (const float2*)emb, emb16, n2, dst, cntT, E, G, chunk3, NCHUNK2);

        scan_reduceB<<<numB3, SB, 0, stream>>>(cntT, partial, M3);
        scan_partials<<<1, SB, 0, stream>>>(partial, blockoff, scanT, numB3, M3);
        scan_applyB<<<numB3, SB, 0, stream>>>(cntT, blockoff, scanT, M3);

        partition_sort<<<NCHUNK2, block, 0, stream>>>(src, dst, w, cntT, scanT,
                                                      stream8, E, G, chunk3);
        group_csr2<<<G, block, 0, stream>>>(stream8, scanT, packed, offsets,
                                            N, E);

        int gridN = (N + 3) / 4;
        gatherV_kernel<<<gridN, 256, 0, stream>>>((const char*)emb16, offsets,
                                                  packed, out, N);
    } else if (ws_size >= neededA && numB <= 1024) {
        int* counts   = (int*)d_ws;              // N
        int* offsets  = counts + N;              // N+1
        int* partial  = offsets + N + 1;
        int* blockoff = partial + numB;
        unsigned int* packed = (unsigned int*)(blockoff + numB);   // E
        unsigned short* ranks = (unsigned short*)((char*)d_ws + ranksOff);
        __half2* emb16 = (__half2*)((char*)d_ws + embOffA);

        hipMemsetAsync(counts, 0, (size_t)N * sizeof(int), stream);

        int n2 = N * (EMB_D / 2);
        p1_cast_hist_ranks<<<CAST_BLOCKS + 1024, block, 0, stream>>>(
            (const float2*)emb, emb16, n2, dst, counts, ranks, E);

        scan_reduceB<<<numB, SB, 0, stream>>>(counts, partial, N);
        scan_partials<<<1, SB, 0, stream>>>(partial, blockoff, offsets, numB, N);
        scan_applyB<<<numB, SB, 0, stream>>>(counts, blockoff, offsets, N);

        int span = (N + 7) / 8;
        bucketR_kernel<<<8 * 256, block, 0, stream>>>(src, dst, w, ranks,
                                                      offsets, packed, E, span, N);

        int gridN = (N + 3) / 4;
        gatherV_kernel<<<gridN, 256, 0, stream>>>((const char*)emb16, offsets,
                                                  packed, out, N);
    } else {
        hipMemsetAsync(d_out, 0, (size_t)out_size * sizeof(float), stream);
        long long total = (long long)E * 16;
        int grid = (int)((total + block - 1) / block);
        lightgcn_scatter<<<grid, block, 0, stream>>>(emb, w, src, dst, out, E);
        int gridN = (N + 3) / 4;
        lightgcn_normalize<<<gridN, 256, 0, stream>>>(out, N);
    }
}

// Round 5
// 191.057 us; speedup vs baseline: 5.5451x; 5.5451x over previous
//
#include <hip/hip_runtime.h>
#include <hip/hip_fp16.h>

#define EMB_D 64
#define SB 1024     // scan block size
#define SPAN 128    // nodes per group (pow2: group = dst>>7, local = dst&127)
#define MAXG 1024   // max groups for LDS arrays
#define NCHUNK2 512 // edge chunks
#define CHMAX 4096  // max edges per chunk for LDS record buffer (32 KB)
#define TILE 4096   // gather_fused tile (records)
#define CAST_BLOCKS 256

// ===========================================================================
// Tier A5: zero global atomics, 5 kernels.
//   A1 : fused fp16 cast + per-chunk group histogram (LDS atomics)
//   scan: 3-phase over [G][NCHUNK2] -> per-(chunk,group) global bases
//   PS : per-chunk LDS counting sort -> stream8 (group-contiguous, coalesced)
//   GF : gather_fused: block per group; per tile: LDS copy + node hist +
//        scan + node-sorted place, then 16-lane crews gather rows with
//        2-deep pipeline into persistent REGISTER accumulators; fused norm.
//        (replaces group_csr2 + gatherV: no packed/offsets, one less pass)
// Tier A3: partition + CSR + gatherV (proven ~190 us) as fallback.
// Tier C : atomic scatter fallback.
// R4 lesson: LDS-atomic accumulation is ~100x too slow; random row fetch
// plateaus at ~3.4 TB/s and ~153 MB FETCH is its structural floor.
// ===========================================================================

__device__ __forceinline__ float h15_to_float(unsigned int bits) {
    return __half2float(__ushort_as_half((unsigned short)bits));
}

// --- A1: fused cast + chunked group histogram (no global atomics) ---------
__global__ void a1_cast_hist(const float2* __restrict__ embin,
                             __half2* __restrict__ emb16, int n2,
                             const int* __restrict__ dst,
                             int* __restrict__ cntT,   // [G][NCHUNK2]
                             int E, int G, int chunk) {
    if (blockIdx.x < CAST_BLOCKS) {
        int i = blockIdx.x * blockDim.x + threadIdx.x;
        int st = CAST_BLOCKS * blockDim.x;
        for (; i < n2; i += st)
            emb16[i] = __float22half2_rn(embin[i]);
    } else {
        __shared__ int bins[MAXG];
        int hb = blockIdx.x - CAST_BLOCKS;
        for (int g = threadIdx.x; g < G; g += blockDim.x) bins[g] = 0;
        __syncthreads();
        int beg = hb * chunk;
        int end = min(beg + chunk, E);
        for (int i = beg + threadIdx.x; i < end; i += blockDim.x)
            atomicAdd(&bins[dst[i] >> 7], 1);
        __syncthreads();
        for (int g = threadIdx.x; g < G; g += blockDim.x)
            cntT[g * NCHUNK2 + hb] = bins[g];
    }
}

// --- generic 3-phase exclusive scan ---------------------------------------
__global__ void scan_reduceB(const int* __restrict__ counts,
                             int* __restrict__ partial, int M) {
    __shared__ int wsum[16];
    const int tid = threadIdx.x, lane = tid & 63, wid = tid >> 6;
    int i = blockIdx.x * SB + tid;
    int v = (i < M) ? counts[i] : 0;
    #pragma unroll
    for (int off = 32; off > 0; off >>= 1)
        v += __shfl_xor(v, off, 64);
    if (lane == 0) wsum[wid] = v;
    __syncthreads();
    if (tid == 0) {
        int s = 0;
        #pragma unroll
        for (int k = 0; k < 16; ++k) s += wsum[k];
        partial[blockIdx.x] = s;
    }
}

// multi-pass: handles any numB (sequential 1024-wide scans w/ carry)
__global__ void scan_partials(const int* __restrict__ partial,
                              int* __restrict__ blockoff,
                              int* __restrict__ offsets, int numB, int M) {
    __shared__ int wsum[16];
    __shared__ int wpre[16];
    __shared__ int carry;
    const int tid = threadIdx.x, lane = tid & 63, wid = tid >> 6;
    if (tid == 0) carry = 0;
    const int nPass = (numB + SB - 1) / SB;
    for (int p = 0; p < nPass; ++p) {
        __syncthreads();
        int base = carry;
        int idx = p * SB + tid;
        int v = (idx < numB) ? partial[idx] : 0;
        int x = v;
        #pragma unroll
        for (int off = 1; off < 64; off <<= 1) {
            int t = __shfl_up(x, off, 64);
            if (lane >= off) x += t;
        }
        if (lane == 63) wsum[wid] = x;
        __syncthreads();
        if (wid == 0) {
            int s = (lane < 16) ? wsum[lane] : 0;
            #pragma unroll
            for (int off = 1; off < 16; off <<= 1) {
                int t = __shfl_up(s, off, 64);
                if (lane >= off) s += t;
            }
            if (lane < 16) wpre[lane] = s;
        }
        __syncthreads();
        int excl = base + ((wid > 0) ? wpre[wid - 1] : 0) + (x - v);
        if (idx < numB) blockoff[idx] = excl;
        __syncthreads();
        if (tid == 0) carry = base + wpre[15];
    }
    __syncthreads();
    if (tid == 0) offsets[M] = carry;   // grand total = E
}

__global__ void scan_applyB(const int* __restrict__ counts,
                            const int* __restrict__ blockoff,
                            int* __restrict__ offsets, int M) {
    __shared__ int wsum[16];
    __shared__ int wpre[16];
    const int tid = threadIdx.x, lane = tid & 63, wid = tid >> 6;
    int i = blockIdx.x * SB + tid;
    int v = (i < M) ? counts[i] : 0;
    int x = v;
    #pragma unroll
    for (int off = 1; off < 64; off <<= 1) {
        int t = __shfl_up(x, off, 64);
        if (lane >= off) x += t;
    }
    if (lane == 63) wsum[wid] = x;
    __syncthreads();
    if (wid == 0) {
        int s = (lane < 16) ? wsum[lane] : 0;
        #pragma unroll
        for (int off = 1; off < 16; off <<= 1) {
            int t = __shfl_up(s, off, 64);
            if (lane >= off) s += t;
        }
        if (lane < 16) wpre[lane] = s;
    }
    __syncthreads();
    int excl = blockoff[blockIdx.x] + ((wid > 0) ? wpre[wid - 1] : 0) + (x - v);
    if (i < M) offsets[i] = excl;
}

// --- PS: per-chunk LDS counting sort + linear coalesced drain -------------
__global__ __launch_bounds__(256) void partition_sort(
        const int* __restrict__ src,
        const int* __restrict__ dst,
        const float* __restrict__ w,
        const int* __restrict__ cntT,    // [G][NCHUNK2]
        const int* __restrict__ scanT,   // [G*NCHUNK2+1]
        uint2* __restrict__ stream8,     // [E]
        int E, int G, int chunk) {
    __shared__ uint2 recs[CHMAX];        // 32 KB
    __shared__ int cur[MAXG];
    __shared__ int delta[MAXG];
    __shared__ int wtot[4];

    const int tid = threadIdx.x, lane = tid & 63, wv = tid >> 6;
    const int b = blockIdx.x;
    const int beg = b * chunk;
    const int end = min(beg + chunk, E);
    const int n = end - beg;

    const int K = (G + 255) >> 8;
    int vals[4];
    int acc = 0;
    #pragma unroll
    for (int k = 0; k < 4; ++k) {
        int g = tid * K + k;
        int c = (k < K && g < G) ? cntT[g * NCHUNK2 + b] : 0;
        vals[k] = c;
        acc += c;
    }
    int x = acc;
    #pragma unroll
    for (int off = 1; off < 64; off <<= 1) {
        int t = __shfl_up(x, off, 64);
        if (lane >= off) x += t;
    }
    if (lane == 63) wtot[wv] = x;
    __syncthreads();
    int woff = 0;
    #pragma unroll
    for (int k2 = 0; k2 < 4; ++k2)
        woff += (k2 < wv) ? wtot[k2] : 0;
    int run = woff + x - acc;
    #pragma unroll
    for (int k = 0; k < 4; ++k) {
        int g = tid * K + k;
        if (k < K && g < G) {
            cur[g] = run;
            delta[g] = scanT[g * NCHUNK2 + b] - run;
            run += vals[k];
        }
    }
    __syncthreads();

    for (int i = beg + tid; i < end; i += blockDim.x) {
        int d = dst[i];
        unsigned int wb = __half_as_ushort(__float2half_rn(w[i]));
        unsigned int pk = ((unsigned int)src[i] << 15) | (wb & 0x7FFFu);
        int g = d >> 7;
        int j = atomicAdd(&cur[g], 1);
        recs[j] = make_uint2(pk, (unsigned int)(d & (SPAN - 1)) |
                                 ((unsigned int)g << 7));
    }
    __syncthreads();

    for (int j = tid; j < n; j += blockDim.x) {
        uint2 r = recs[j];
        int g = (int)(r.y >> 7);
        stream8[delta[g] + j] = make_uint2(r.x, r.y & (SPAN - 1u));
    }
}

// --- GF: fused per-group CSR + register-accumulate gather + normalize -----
// Crew = 16 contiguous lanes; crew c owns nodes {c, c+32, c+64, c+96}.
// Lane ql covers dims [4*ql, 4*ql+4) via one uint2 (8B) of the 128B row.
__global__ __launch_bounds__(512) void gather_fused(
        const char* __restrict__ emb16b,      // row v at byte v*128
        const uint2* __restrict__ stream8,    // [E] {pk, dl}
        const int* __restrict__ scanT,        // [G*NCHUNK2+1]
        float* __restrict__ out, int N) {
    __shared__ uint2 lrec[TILE];              // 32 KB
    __shared__ unsigned int srt[TILE];        // 16 KB
    __shared__ int hcnt[SPAN];
    __shared__ int nstart[SPAN];
    __shared__ int cur[SPAN];
    __shared__ int wtot[2];

    const int g = blockIdx.x;
    const int tid = threadIdx.x;
    const int lane = tid & 63, wv = tid >> 6;
    const int base = scanT[g * NCHUNK2];
    const int endE = scanT[(g + 1) * NCHUNK2];   // last group -> scanT[M]=E
    const int crew = tid >> 4;                   // 0..31
    const int ql = tid & 15;
    const unsigned qlo = (unsigned)(ql << 3);

    float4 acc[4];
    #pragma unroll
    for (int ni = 0; ni < 4; ++ni) acc[ni] = make_float4(0.f, 0.f, 0.f, 0.f);

    for (int tb = base; tb < endE; tb += TILE) {
        const int n = min(TILE, endE - tb);
        if (tid < SPAN) hcnt[tid] = 0;
        __syncthreads();
        // tile copy + node histogram
        for (int j = tid; j < n; j += 512) {
            uint2 r = stream8[tb + j];
            lrec[j] = r;
            atomicAdd(&hcnt[r.y], 1);
        }
        __syncthreads();
        // exclusive scan of 128 counters (waves 0-1)
        int v = (tid < SPAN) ? hcnt[tid] : 0;
        int x = v;
        #pragma unroll
        for (int off = 1; off < 64; off <<= 1) {
            int t = __shfl_up(x, off, 64);
            if (lane >= off) x += t;
        }
        if (wv < 2 && lane == 63) wtot[wv] = x;
        __syncthreads();
        if (tid < SPAN) {
            int excl = x - v + ((wv == 1) ? wtot[0] : 0);
            nstart[tid] = excl;
            cur[tid] = excl;
        }
        __syncthreads();
        // node-sorted place
        for (int j = tid; j < n; j += 512) {
            uint2 r = lrec[j];
            int slot = atomicAdd(&cur[r.y], 1);
            srt[slot] = r.x;
        }
        __syncthreads();
        // gather: each crew walks its 4 nodes' tile-lists (2-deep pipeline)
        #pragma unroll
        for (int ni = 0; ni < 4; ++ni) {
            int nd = crew + (ni << 5);
            int s = nstart[nd];
            int e = cur[nd];
            float4 a = acc[ni];
            unsigned int pk0 = (s < e) ? srt[s] : 0u;
            uint2 r0 = *reinterpret_cast<const uint2*>(
                emb16b + ((pk0 >> 15) * 128u + qlo));
            for (int k = s; k < e; ++k) {
                unsigned int pk1 = (k + 1 < e) ? srt[k + 1] : 0u;
                uint2 r1 = *reinterpret_cast<const uint2*>(
                    emb16b + ((pk1 >> 15) * 128u + qlo));   // next in flight
                float wt = h15_to_float(pk0 & 0x7FFFu);
                float2 x01 = __half22float2(*reinterpret_cast<__half2*>(&r0.x));
                float2 x23 = __half22float2(*reinterpret_cast<__half2*>(&r0.y));
                a.x = fmaf(x01.x, wt, a.x);
                a.y = fmaf(x01.y, wt, a.y);
                a.z = fmaf(x23.x, wt, a.z);
                a.w = fmaf(x23.y, wt, a.w);
                pk0 = pk1; r0 = r1;
            }
            acc[ni] = a;
        }
        __syncthreads();
    }

    // normalize + write (crew-local reduce: offsets 1,2,4,8 stay in crew)
    #pragma unroll
    for (int ni = 0; ni < 4; ++ni) {
        int node = g * SPAN + crew + (ni << 5);
        float4 a = acc[ni];
        float ss = a.x * a.x + a.y * a.y + a.z * a.z + a.w * a.w;
        ss += __shfl_xor(ss, 1, 64);
        ss += __shfl_xor(ss, 2, 64);
        ss += __shfl_xor(ss, 4, 64);
        ss += __shfl_xor(ss, 8, 64);
        float scale = 1.0f / fmaxf(sqrtf(ss), 1e-12f);
        if (node < N) {
            float4 o = make_float4(a.x * scale, a.y * scale,
                                   a.z * scale, a.w * scale);
            *reinterpret_cast<float4*>(out + (size_t)node * EMB_D
                                       + (ql << 2)) = o;
        }
    }
}

// ===========================================================================
// Tier A3 fallback kernels (proven ~190 us path)
// ===========================================================================
__global__ void group_csr2(const uint2* __restrict__ stream8,
                           const int* __restrict__ scanT,
                           unsigned int* __restrict__ packed,
                           int* __restrict__ offsets, int N, int E) {
    __shared__ int hcnt[SPAN];
    __shared__ int cur[SPAN];
    __shared__ int wtot[4];
    int g = blockIdx.x;
    int tid = threadIdx.x;
    int base = scanT[g * NCHUNK2];
    int endE = scanT[(g + 1) * NCHUNK2];
    if (tid < SPAN) hcnt[tid] = 0;
    __syncthreads();
    for (int i = base + tid; i < endE; i += blockDim.x)
        atomicAdd(&hcnt[stream8[i].y], 1);
    __syncthreads();
    int v = (tid < SPAN) ? hcnt[tid] : 0;
    int lane = tid & 63, wv = tid >> 6;
    int x = v;
    #pragma unroll
    for (int off = 1; off < 64; off <<= 1) {
        int t = __shfl_up(x, off, 64);
        if (lane >= off) x += t;
    }
    if (lane == 63) wtot[wv] = x;
    __syncthreads();
    if (tid < SPAN) {
        int excl = x - v + ((wv == 1) ? wtot[0] : 0);
        cur[tid] = base + excl;
        int node = g * SPAN + tid;
        if (node < N) offsets[node] = base + excl;
    }
    if (g == 0 && tid == 0) offsets[N] = E;
    __syncthreads();
    for (int i = base + tid; i < endE; i += blockDim.x) {
        uint2 r = stream8[i];
        int slot = atomicAdd(&cur[r.y], 1);
        packed[slot] = r.x;
    }
}

__global__ __launch_bounds__(256) void gatherV_kernel(
        const char* __restrict__ emb16b,
        const int* __restrict__ offsets,
        const unsigned int* __restrict__ packed,
        float* __restrict__ out, int N) {
    int node = blockIdx.x * 4 + (threadIdx.x >> 6);
    int lane = threadIdx.x & 63;
    if (node >= N) return;
    int q  = lane >> 3;
    int ql = lane & 7;
    const unsigned qlo = (unsigned)(ql << 4);

    int beg = offsets[node];
    int end = offsets[node + 1];

    float a0=0.f,a1=0.f,a2=0.f,a3=0.f,a4=0.f,a5=0.f,a6=0.f,a7=0.f;

    int idx0 = beg + q;
    int idx1 = idx0 + 8;
    int idx2 = idx1 + 8;
    unsigned int pk0 = (idx0 < end) ? packed[idx0] : 0u;
    unsigned int pk1 = (idx1 < end) ? packed[idx1] : 0u;
    unsigned int pk2 = (idx2 < end) ? packed[idx2] : 0u;
    uint4 r0 = *reinterpret_cast<const uint4*>(emb16b + ((pk0 >> 15) * 128u + qlo));
    uint4 r1 = *reinterpret_cast<const uint4*>(emb16b + ((pk1 >> 15) * 128u + qlo));

    for (int j = beg; j < end; j += 8) {
        uint4 r2 = *reinterpret_cast<const uint4*>(
            emb16b + ((pk2 >> 15) * 128u + qlo));
        int idx3 = idx2 + 8;
        unsigned int pk3 = (idx3 < end) ? packed[idx3] : 0u;

        float wt = h15_to_float(pk0 & 0x7FFFu);
        float2 x01 = __half22float2(*reinterpret_cast<__half2*>(&r0.x));
        float2 x23 = __half22float2(*reinterpret_cast<__half2*>(&r0.y));
        float2 x45 = __half22float2(*reinterpret_cast<__half2*>(&r0.z));
        float2 x67 = __half22float2(*reinterpret_cast<__half2*>(&r0.w));
        a0 = fmaf(x01.x, wt, a0);
        a1 = fmaf(x01.y, wt, a1);
        a2 = fmaf(x23.x, wt, a2);
        a3 = fmaf(x23.y, wt, a3);
        a4 = fmaf(x45.x, wt, a4);
        a5 = fmaf(x45.y, wt, a5);
        a6 = fmaf(x67.x, wt, a6);
        a7 = fmaf(x67.y, wt, a7);

        pk0 = pk1; pk1 = pk2; pk2 = pk3;
        r0 = r1; r1 = r2;
        idx2 = idx3;
    }

    #pragma unroll
    for (int off = 8; off < 64; off <<= 1) {
        a0 += __shfl_xor(a0, off, 64);
        a1 += __shfl_xor(a1, off, 64);
        a2 += __shfl_xor(a2, off, 64);
        a3 += __shfl_xor(a3, off, 64);
        a4 += __shfl_xor(a4, off, 64);
        a5 += __shfl_xor(a5, off, 64);
        a6 += __shfl_xor(a6, off, 64);
        a7 += __shfl_xor(a7, off, 64);
    }
    float ss = a0*a0 + a1*a1 + a2*a2 + a3*a3 + a4*a4 + a5*a5 + a6*a6 + a7*a7;
    ss += __shfl_xor(ss, 1, 64);
    ss += __shfl_xor(ss, 2, 64);
    ss += __shfl_xor(ss, 4, 64);
    float scale = 1.0f / fmaxf(sqrtf(ss), 1e-12f);

    if (q == 0) {
        float4* po = reinterpret_cast<float4*>(out + (size_t)node * EMB_D
                                               + (ql << 3));
        po[0] = make_float4(a0 * scale, a1 * scale, a2 * scale, a3 * scale);
        po[1] = make_float4(a4 * scale, a5 * scale, a6 * scale, a7 * scale);
    }
}

// ===========================================================================
// Tier C: atomic scatter fallback.
// ===========================================================================
__global__ void lightgcn_scatter(const float* __restrict__ emb,
                                 const float* __restrict__ w,
                                 const int* __restrict__ src,
                                 const int* __restrict__ dst,
                                 float* __restrict__ h, int E) {
    long long t = (long long)blockIdx.x * blockDim.x + threadIdx.x;
    int e = (int)(t >> 4);
    int d = (int)(t & 15) << 2;
    if (e >= E) return;
    int s = src[e]; int v = dst[e]; float wt = w[e];
    const float4 m = *reinterpret_cast<const float4*>(emb + (size_t)s * EMB_D + d);
    float* o = h + (size_t)v * EMB_D + d;
    unsafeAtomicAdd(o + 0, m.x * wt);
    unsafeAtomicAdd(o + 1, m.y * wt);
    unsafeAtomicAdd(o + 2, m.z * wt);
    unsafeAtomicAdd(o + 3, m.w * wt);
}

__global__ void lightgcn_normalize(float* __restrict__ h, int N) {
    int row = blockIdx.x * (blockDim.x >> 6) + (threadIdx.x >> 6);
    int lane = threadIdx.x & 63;
    if (row >= N) return;
    float x = h[(size_t)row * EMB_D + lane];
    float ss = x * x;
    #pragma unroll
    for (int off = 32; off > 0; off >>= 1)
        ss += __shfl_xor(ss, off, 64);
    h[(size_t)row * EMB_D + lane] = x / fmaxf(sqrtf(ss), 1e-12f);
}

extern "C" void kernel_launch(void* const* d_in, const int* in_sizes, int n_in,
                              void* d_out, int out_size, void* d_ws, size_t ws_size,
                              hipStream_t stream) {
    const float* emb = (const float*)d_in[0];   // [N, 64] fp32
    const float* w   = (const float*)d_in[1];   // [E] fp32
    const int*   src = (const int*)d_in[2];     // [E] int32
    const int*   dst = (const int*)d_in[3];     // [E] int32
    float* out = (float*)d_out;

    const int N = in_sizes[0] / EMB_D;
    const int E = in_sizes[1];
    const int block = 256;
    const int G = (N + SPAN - 1) / SPAN;

    const int M3 = G * NCHUNK2;
    const int numB3 = (M3 + SB - 1) / SB;
    const int chunk3 = (E + NCHUNK2 - 1) / NCHUNK2;

    // ---- Tier A5 workspace: cntT[M3] | scanT[M3+1] | partial | blockoff |
    //      pad | stream8[E] uint2 | pad | emb16  (~27.4 MB) ----
    size_t intsA5 = (size_t)M3 + (size_t)(M3 + 1) + 2 * (size_t)numB3;
    size_t strOff5 = (intsA5 * sizeof(int) + 15) & ~(size_t)15;
    size_t embOff5 = (strOff5 + (size_t)E * sizeof(uint2) + 15) & ~(size_t)15;
    size_t neededA5 = embOff5 + (size_t)N * EMB_D * sizeof(__half);

    // ---- Tier A3 workspace (~35.7 MB) ----
    size_t intsA3 = (size_t)M3 + (size_t)(M3 + 1) + 2 * (size_t)numB3
                  + (size_t)(N + 1);
    size_t strOff = (intsA3 * sizeof(int) + 15) & ~(size_t)15;
    size_t pkdOff = strOff + (size_t)E * sizeof(uint2);
    size_t embOff3 = (pkdOff + (size_t)E * sizeof(unsigned int) + 15)
                     & ~(size_t)15;
    size_t neededA3 = embOff3 + (size_t)N * EMB_D * sizeof(__half);

    if (ws_size >= neededA5 && G <= MAXG && chunk3 <= CHMAX &&
        E < (1 << 28) && N < (1 << 17)) {
        int* cntT     = (int*)d_ws;              // M3
        int* scanT    = cntT + M3;               // M3+1
        int* partial  = scanT + M3 + 1;          // numB3
        int* blockoff = partial + numB3;         // numB3
        uint2* stream8 = (uint2*)((char*)d_ws + strOff5);   // E
        __half2* emb16 = (__half2*)((char*)d_ws + embOff5);

        int n2 = N * (EMB_D / 2);

        a1_cast_hist<<<CAST_BLOCKS + NCHUNK2, block, 0, stream>>>(
            (const float2*)emb, emb16, n2, dst, cntT, E, G, chunk3);

        scan_reduceB<<<numB3, SB, 0, stream>>>(cntT, partial, M3);
        scan_partials<<<1, SB, 0, stream>>>(partial, blockoff, scanT, numB3, M3);
        scan_applyB<<<numB3, SB, 0, stream>>>(cntT, blockoff, scanT, M3);

        partition_sort<<<NCHUNK2, block, 0, stream>>>(src, dst, w, cntT, scanT,
                                                      stream8, E, G, chunk3);

        gather_fused<<<G, 512, 0, stream>>>((const char*)emb16, stream8,
                                            scanT, out, N);
    } else if (ws_size >= neededA3 && G <= MAXG && chunk3 <= CHMAX &&
               E < (1 << 28) && N < (1 << 17)) {
        int* cntT     = (int*)d_ws;              // M3
        int* scanT    = cntT + M3;               // M3+1
        int* partial  = scanT + M3 + 1;          // numB3
        int* blockoff = partial + numB3;         // numB3
        int* offsets  = blockoff + numB3;        // N+1
        uint2* stream8 = (uint2*)((char*)d_ws + strOff);                // E
        unsigned int* packed = (unsigned int*)((char*)d_ws + pkdOff);   // E
        __half2* emb16 = (__half2*)((char*)d_ws + embOff3);

        int n2 = N * (EMB_D / 2);

        a1_cast_hist<<<CAST_BLOCKS + NCHUNK2, block, 0, stream>>>(
            (const float2*)emb, emb16, n2, dst, cntT, E, G, chunk3);

        scan_reduceB<<<numB3, SB, 0, stream>>>(cntT, partial, M3);
        scan_partials<<<1, SB, 0, stream>>>(partial, blockoff, scanT, numB3, M3);
        scan_applyB<<<numB3, SB, 0, stream>>>(cntT, blockoff, scanT, M3);

        partition_sort<<<NCHUNK2, block, 0, stream>>>(src, dst, w, cntT, scanT,
                                                      stream8, E, G, chunk3);
        group_csr2<<<G, block, 0, stream>>>(stream8, scanT, packed, offsets,
                                            N, E);

        int gridN = (N + 3) / 4;
        gatherV_kernel<<<gridN, 256, 0, stream>>>((const char*)emb16, offsets,
                                                  packed, out, N);
    } else {
        hipMemsetAsync(d_out, 0, (size_t)out_size * sizeof(float), stream);
        long long total = (long long)E * 16;
        int grid = (int)((total + block - 1) / block);
        lightgcn_scatter<<<grid, block, 0, stream>>>(emb, w, src, dst, out, E);
        int gridN = (N + 3) / 4;
        lightgcn_normalize<<<gridN, 256, 0, stream>>>(out, N);
    }
}

// Round 6
// 175.381 us; speedup vs baseline: 6.0408x; 1.0894x over previous
//
#include <hip/hip_runtime.h>
#include <hip/hip_fp16.h>

#define EMB_D 64
#define SB 1024     // scan block size
#define SPAN 128    // nodes per group (pow2: group = dst>>7, local = dst&127)
#define MAXG 1024   // max groups for LDS arrays
#define NCHUNK2 512 // edge chunks
#define CHMAX 4096  // max edges per chunk for LDS record buffer (32 KB)
#define TILE 4096   // gather_fused tile (records)
#define CAST_BLOCKS 256

// ===========================================================================
// Tier A6: zero global atomics, 5 kernels (R5 structure, two perf fixes).
//   A1 : fused fp16 cast + per-chunk group histogram (LDS atomics)
//   scan: 3-phase over [G][NCHUNK2] -> per-(chunk,group) global bases
//   PS : per-chunk LDS counting sort -> stream8 (group-contiguous drain),
//        NOW 512 threads/block (16 waves/CU, was 8) for latency hiding.
//   GF : gather_fused: per-group block; tile: LDS copy+hist+scan+place,
//        then crews gather rows into register accumulators; fused norm.
//        NOW 2x8-lane substreams per crew, uint4 rows, 2-deep each
//        -> 16 rows in flight per wave (gatherV-class MLP).
// Tier A3: partition + CSR + gatherV (proven ~190 us) as fallback.
// Tier C : atomic scatter fallback.
// R4 lesson: LDS-atomic accumulation ~100x too slow; random row fetch
// plateaus ~3.4 TB/s, ~150 MB FETCH is its structural floor.
// ===========================================================================

__device__ __forceinline__ float h15_to_float(unsigned int bits) {
    return __half2float(__ushort_as_half((unsigned short)bits));
}

// --- A1: fused cast + chunked group histogram (no global atomics) ---------
__global__ void a1_cast_hist(const float2* __restrict__ embin,
                             __half2* __restrict__ emb16, int n2,
                             const int* __restrict__ dst,
                             int* __restrict__ cntT,   // [G][NCHUNK2]
                             int E, int G, int chunk) {
    if (blockIdx.x < CAST_BLOCKS) {
        int i = blockIdx.x * blockDim.x + threadIdx.x;
        int st = CAST_BLOCKS * blockDim.x;
        for (; i < n2; i += st)
            emb16[i] = __float22half2_rn(embin[i]);
    } else {
        __shared__ int bins[MAXG];
        int hb = blockIdx.x - CAST_BLOCKS;
        for (int g = threadIdx.x; g < G; g += blockDim.x) bins[g] = 0;
        __syncthreads();
        int beg = hb * chunk;
        int end = min(beg + chunk, E);
        for (int i = beg + threadIdx.x; i < end; i += blockDim.x)
            atomicAdd(&bins[dst[i] >> 7], 1);
        __syncthreads();
        for (int g = threadIdx.x; g < G; g += blockDim.x)
            cntT[g * NCHUNK2 + hb] = bins[g];
    }
}

// --- generic 3-phase exclusive scan ---------------------------------------
__global__ void scan_reduceB(const int* __restrict__ counts,
                             int* __restrict__ partial, int M) {
    __shared__ int wsum[16];
    const int tid = threadIdx.x, lane = tid & 63, wid = tid >> 6;
    int i = blockIdx.x * SB + tid;
    int v = (i < M) ? counts[i] : 0;
    #pragma unroll
    for (int off = 32; off > 0; off >>= 1)
        v += __shfl_xor(v, off, 64);
    if (lane == 0) wsum[wid] = v;
    __syncthreads();
    if (tid == 0) {
        int s = 0;
        #pragma unroll
        for (int k = 0; k < 16; ++k) s += wsum[k];
        partial[blockIdx.x] = s;
    }
}

// multi-pass: handles any numB (sequential 1024-wide scans w/ carry)
__global__ void scan_partials(const int* __restrict__ partial,
                              int* __restrict__ blockoff,
                              int* __restrict__ offsets, int numB, int M) {
    __shared__ int wsum[16];
    __shared__ int wpre[16];
    __shared__ int carry;
    const int tid = threadIdx.x, lane = tid & 63, wid = tid >> 6;
    if (tid == 0) carry = 0;
    const int nPass = (numB + SB - 1) / SB;
    for (int p = 0; p < nPass; ++p) {
        __syncthreads();
        int base = carry;
        int idx = p * SB + tid;
        int v = (idx < numB) ? partial[idx] : 0;
        int x = v;
        #pragma unroll
        for (int off = 1; off < 64; off <<= 1) {
            int t = __shfl_up(x, off, 64);
            if (lane >= off) x += t;
        }
        if (lane == 63) wsum[wid] = x;
        __syncthreads();
        if (wid == 0) {
            int s = (lane < 16) ? wsum[lane] : 0;
            #pragma unroll
            for (int off = 1; off < 16; off <<= 1) {
                int t = __shfl_up(s, off, 64);
                if (lane >= off) s += t;
            }
            if (lane < 16) wpre[lane] = s;
        }
        __syncthreads();
        int excl = base + ((wid > 0) ? wpre[wid - 1] : 0) + (x - v);
        if (idx < numB) blockoff[idx] = excl;
        __syncthreads();
        if (tid == 0) carry = base + wpre[15];
    }
    __syncthreads();
    if (tid == 0) offsets[M] = carry;   // grand total = E
}

__global__ void scan_applyB(const int* __restrict__ counts,
                            const int* __restrict__ blockoff,
                            int* __restrict__ offsets, int M) {
    __shared__ int wsum[16];
    __shared__ int wpre[16];
    const int tid = threadIdx.x, lane = tid & 63, wid = tid >> 6;
    int i = blockIdx.x * SB + tid;
    int v = (i < M) ? counts[i] : 0;
    int x = v;
    #pragma unroll
    for (int off = 1; off < 64; off <<= 1) {
        int t = __shfl_up(x, off, 64);
        if (lane >= off) x += t;
    }
    if (lane == 63) wsum[wid] = x;
    __syncthreads();
    if (wid == 0) {
        int s = (lane < 16) ? wsum[lane] : 0;
        #pragma unroll
        for (int off = 1; off < 16; off <<= 1) {
            int t = __shfl_up(s, off, 64);
            if (lane >= off) s += t;
        }
        if (lane < 16) wpre[lane] = s;
    }
    __syncthreads();
    int excl = blockoff[blockIdx.x] + ((wid > 0) ? wpre[wid - 1] : 0) + (x - v);
    if (i < M) offsets[i] = excl;
}

// --- PS: per-chunk LDS counting sort + linear coalesced drain (512 thr) ---
__global__ __launch_bounds__(512) void partition_sort(
        const int* __restrict__ src,
        const int* __restrict__ dst,
        const float* __restrict__ w,
        const int* __restrict__ cntT,    // [G][NCHUNK2]
        const int* __restrict__ scanT,   // [G*NCHUNK2+1]
        uint2* __restrict__ stream8,     // [E]
        int E, int G, int chunk) {
    __shared__ uint2 recs[CHMAX];        // 32 KB
    __shared__ int cur[MAXG];
    __shared__ int delta[MAXG];
    __shared__ int wtot[8];

    const int tid = threadIdx.x, lane = tid & 63, wv = tid >> 6;
    const int b = blockIdx.x;
    const int beg = b * chunk;
    const int end = min(beg + chunk, E);
    const int n = end - beg;

    const int K = (G + 511) >> 9;        // <= 2 (G <= MAXG, 512 threads)
    int vals[2];
    int acc = 0;
    #pragma unroll
    for (int k = 0; k < 2; ++k) {
        int g = tid * K + k;
        int c = (k < K && g < G) ? cntT[g * NCHUNK2 + b] : 0;
        vals[k] = c;
        acc += c;
    }
    int x = acc;
    #pragma unroll
    for (int off = 1; off < 64; off <<= 1) {
        int t = __shfl_up(x, off, 64);
        if (lane >= off) x += t;
    }
    if (lane == 63) wtot[wv] = x;
    __syncthreads();
    int woff = 0;
    #pragma unroll
    for (int k2 = 0; k2 < 8; ++k2)
        woff += (k2 < wv) ? wtot[k2] : 0;
    int run = woff + x - acc;            // exclusive prefix (local base)
    #pragma unroll
    for (int k = 0; k < 2; ++k) {
        int g = tid * K + k;
        if (k < K && g < G) {
            cur[g] = run;
            delta[g] = scanT[g * NCHUNK2 + b] - run;
            run += vals[k];
        }
    }
    __syncthreads();

    for (int i = beg + tid; i < end; i += 512) {
        int d = dst[i];
        unsigned int wb = __half_as_ushort(__float2half_rn(w[i]));
        unsigned int pk = ((unsigned int)src[i] << 15) | (wb & 0x7FFFu);
        int g = d >> 7;
        int j = atomicAdd(&cur[g], 1);
        recs[j] = make_uint2(pk, (unsigned int)(d & (SPAN - 1)) |
                                 ((unsigned int)g << 7));
    }
    __syncthreads();

    for (int j = tid; j < n; j += 512) {
        uint2 r = recs[j];
        int g = (int)(r.y >> 7);
        stream8[delta[g] + j] = make_uint2(r.x, r.y & (SPAN - 1u));
    }
}

// --- GF: fused per-group CSR + register-accumulate gather + normalize -----
// Crew = 16 lanes owns nodes {c, c+32, c+64, c+96}; crew splits into two
// 8-lane substreams (sub = records k0+sub, step 2), each 2-deep pipelined,
// lane sl loads uint4 = dims [sl*8, sl*8+8) -> 16 rows in flight per wave.
__global__ __launch_bounds__(512) void gather_fused(
        const char* __restrict__ emb16b,      // row v at byte v*128
        const uint2* __restrict__ stream8,    // [E] {pk, dl}
        const int* __restrict__ scanT,        // [G*NCHUNK2+1]
        float* __restrict__ out, int N) {
    __shared__ uint2 lrec[TILE];              // 32 KB
    __shared__ unsigned int srt[TILE];        // 16 KB
    __shared__ int hcnt[SPAN];
    __shared__ int nstart[SPAN];
    __shared__ int cur[SPAN];
    __shared__ int wtot[2];

    const int g = blockIdx.x;
    const int tid = threadIdx.x;
    const int lane = tid & 63, wv = tid >> 6;
    const int base = scanT[g * NCHUNK2];
    const int endE = scanT[(g + 1) * NCHUNK2];   // last group -> scanT[M]=E
    const int crew = tid >> 4;                   // 0..31
    const int ql = tid & 15;
    const int sub = ql >> 3;                     // substream 0/1
    const int sl = ql & 7;                       // 16B segment of row
    const unsigned qlo = (unsigned)(sl << 4);

    float4 accA[4], accB[4];                  // dims sl*8+0..3 / +4..7
    #pragma unroll
    for (int ni = 0; ni < 4; ++ni) {
        accA[ni] = make_float4(0.f, 0.f, 0.f, 0.f);
        accB[ni] = make_float4(0.f, 0.f, 0.f, 0.f);
    }

    for (int tb = base; tb < endE; tb += TILE) {
        const int n = min(TILE, endE - tb);
        if (tid < SPAN) hcnt[tid] = 0;
        __syncthreads();
        // tile copy + node histogram
        for (int j = tid; j < n; j += 512) {
            uint2 r = stream8[tb + j];
            lrec[j] = r;
            atomicAdd(&hcnt[r.y], 1);
        }
        __syncthreads();
        // exclusive scan of 128 counters (waves 0-1)
        int v = (tid < SPAN) ? hcnt[tid] : 0;
        int x = v;
        #pragma unroll
        for (int off = 1; off < 64; off <<= 1) {
            int t = __shfl_up(x, off, 64);
            if (lane >= off) x += t;
        }
        if (wv < 2 && lane == 63) wtot[wv] = x;
        __syncthreads();
        if (tid < SPAN) {
            int excl = x - v + ((wv == 1) ? wtot[0] : 0);
            nstart[tid] = excl;
            cur[tid] = excl;
        }
        __syncthreads();
        // node-sorted place
        for (int j = tid; j < n; j += 512) {
            uint2 r = lrec[j];
            int slot = atomicAdd(&cur[r.y], 1);
            srt[slot] = r.x;
        }
        __syncthreads();
        // gather: each crew's 2 substreams walk its 4 nodes' tile-lists
        #pragma unroll
        for (int ni = 0; ni < 4; ++ni) {
            int nd = crew + (ni << 5);
            int s = nstart[nd];
            int e = cur[nd];
            float4 aA = accA[ni];
            float4 aB = accB[ni];
            int k0 = s + sub;
            unsigned int pk0 = (k0 < e) ? srt[k0] : 0u;
            uint4 r0 = *reinterpret_cast<const uint4*>(
                emb16b + ((pk0 >> 15) * 128u + qlo));
            for (int k = k0; k < e; k += 2) {
                int k1 = k + 2;
                unsigned int pk1 = (k1 < e) ? srt[k1] : 0u;
                uint4 r1 = *reinterpret_cast<const uint4*>(
                    emb16b + ((pk1 >> 15) * 128u + qlo));   // next in flight
                float wt = h15_to_float(pk0 & 0x7FFFu);
                float2 x01 = __half22float2(*reinterpret_cast<__half2*>(&r0.x));
                float2 x23 = __half22float2(*reinterpret_cast<__half2*>(&r0.y));
                float2 x45 = __half22float2(*reinterpret_cast<__half2*>(&r0.z));
                float2 x67 = __half22float2(*reinterpret_cast<__half2*>(&r0.w));
                aA.x = fmaf(x01.x, wt, aA.x);
                aA.y = fmaf(x01.y, wt, aA.y);
                aA.z = fmaf(x23.x, wt, aA.z);
                aA.w = fmaf(x23.y, wt, aA.w);
                aB.x = fmaf(x45.x, wt, aB.x);
                aB.y = fmaf(x45.y, wt, aB.y);
                aB.z = fmaf(x67.x, wt, aB.z);
                aB.w = fmaf(x67.y, wt, aB.w);
                pk0 = pk1; r0 = r1;
            }
            accA[ni] = aA;
            accB[ni] = aB;
        }
        __syncthreads();
    }

    // merge substreams, normalize, write
    #pragma unroll
    for (int ni = 0; ni < 4; ++ni) {
        accA[ni].x += __shfl_xor(accA[ni].x, 8, 64);
        accA[ni].y += __shfl_xor(accA[ni].y, 8, 64);
        accA[ni].z += __shfl_xor(accA[ni].z, 8, 64);
        accA[ni].w += __shfl_xor(accA[ni].w, 8, 64);
        accB[ni].x += __shfl_xor(accB[ni].x, 8, 64);
        accB[ni].y += __shfl_xor(accB[ni].y, 8, 64);
        accB[ni].z += __shfl_xor(accB[ni].z, 8, 64);
        accB[ni].w += __shfl_xor(accB[ni].w, 8, 64);
        int node = g * SPAN + crew + (ni << 5);
        float4 aA = accA[ni];
        float4 aB = accB[ni];
        float ss = aA.x * aA.x + aA.y * aA.y + aA.z * aA.z + aA.w * aA.w
                 + aB.x * aB.x + aB.y * aB.y + aB.z * aB.z + aB.w * aB.w;
        ss += __shfl_xor(ss, 1, 64);
        ss += __shfl_xor(ss, 2, 64);
        ss += __shfl_xor(ss, 4, 64);
        float scale = 1.0f / fmaxf(sqrtf(ss), 1e-12f);
        if (node < N) {
            float4 a = sub ? aB : aA;
            float4 o = make_float4(a.x * scale, a.y * scale,
                                   a.z * scale, a.w * scale);
            *reinterpret_cast<float4*>(out + (size_t)node * EMB_D
                                       + (sl << 3) + (sub << 2)) = o;
        }
    }
}

// ===========================================================================
// Tier A3 fallback kernels (proven ~190 us path)
// ===========================================================================
__global__ void group_csr2(const uint2* __restrict__ stream8,
                           const int* __restrict__ scanT,
                           unsigned int* __restrict__ packed,
                           int* __restrict__ offsets, int N, int E) {
    __shared__ int hcnt[SPAN];
    __shared__ int cur[SPAN];
    __shared__ int wtot[4];
    int g = blockIdx.x;
    int tid = threadIdx.x;
    int base = scanT[g * NCHUNK2];
    int endE = scanT[(g + 1) * NCHUNK2];
    if (tid < SPAN) hcnt[tid] = 0;
    __syncthreads();
    for (int i = base + tid; i < endE; i += blockDim.x)
        atomicAdd(&hcnt[stream8[i].y], 1);
    __syncthreads();
    int v = (tid < SPAN) ? hcnt[tid] : 0;
    int lane = tid & 63, wv = tid >> 6;
    int x = v;
    #pragma unroll
    for (int off = 1; off < 64; off <<= 1) {
        int t = __shfl_up(x, off, 64);
        if (lane >= off) x += t;
    }
    if (lane == 63) wtot[wv] = x;
    __syncthreads();
    if (tid < SPAN) {
        int excl = x - v + ((wv == 1) ? wtot[0] : 0);
        cur[tid] = base + excl;
        int node = g * SPAN + tid;
        if (node < N) offsets[node] = base + excl;
    }
    if (g == 0 && tid == 0) offsets[N] = E;
    __syncthreads();
    for (int i = base + tid; i < endE; i += blockDim.x) {
        uint2 r = stream8[i];
        int slot = atomicAdd(&cur[r.y], 1);
        packed[slot] = r.x;
    }
}

__global__ __launch_bounds__(256) void gatherV_kernel(
        const char* __restrict__ emb16b,
        const int* __restrict__ offsets,
        const unsigned int* __restrict__ packed,
        float* __restrict__ out, int N) {
    int node = blockIdx.x * 4 + (threadIdx.x >> 6);
    int lane = threadIdx.x & 63;
    if (node >= N) return;
    int q  = lane >> 3;
    int ql = lane & 7;
    const unsigned qlo = (unsigned)(ql << 4);

    int beg = offsets[node];
    int end = offsets[node + 1];

    float a0=0.f,a1=0.f,a2=0.f,a3=0.f,a4=0.f,a5=0.f,a6=0.f,a7=0.f;

    int idx0 = beg + q;
    int idx1 = idx0 + 8;
    int idx2 = idx1 + 8;
    unsigned int pk0 = (idx0 < end) ? packed[idx0] : 0u;
    unsigned int pk1 = (idx1 < end) ? packed[idx1] : 0u;
    unsigned int pk2 = (idx2 < end) ? packed[idx2] : 0u;
    uint4 r0 = *reinterpret_cast<const uint4*>(emb16b + ((pk0 >> 15) * 128u + qlo));
    uint4 r1 = *reinterpret_cast<const uint4*>(emb16b + ((pk1 >> 15) * 128u + qlo));

    for (int j = beg; j < end; j += 8) {
        uint4 r2 = *reinterpret_cast<const uint4*>(
            emb16b + ((pk2 >> 15) * 128u + qlo));
        int idx3 = idx2 + 8;
        unsigned int pk3 = (idx3 < end) ? packed[idx3] : 0u;

        float wt = h15_to_float(pk0 & 0x7FFFu);
        float2 x01 = __half22float2(*reinterpret_cast<__half2*>(&r0.x));
        float2 x23 = __half22float2(*reinterpret_cast<__half2*>(&r0.y));
        float2 x45 = __half22float2(*reinterpret_cast<__half2*>(&r0.z));
        float2 x67 = __half22float2(*reinterpret_cast<__half2*>(&r0.w));
        a0 = fmaf(x01.x, wt, a0);
        a1 = fmaf(x01.y, wt, a1);
        a2 = fmaf(x23.x, wt, a2);
        a3 = fmaf(x23.y, wt, a3);
        a4 = fmaf(x45.x, wt, a4);
        a5 = fmaf(x45.y, wt, a5);
        a6 = fmaf(x67.x, wt, a6);
        a7 = fmaf(x67.y, wt, a7);

        pk0 = pk1; pk1 = pk2; pk2 = pk3;
        r0 = r1; r1 = r2;
        idx2 = idx3;
    }

    #pragma unroll
    for (int off = 8; off < 64; off <<= 1) {
        a0 += __shfl_xor(a0, off, 64);
        a1 += __shfl_xor(a1, off, 64);
        a2 += __shfl_xor(a2, off, 64);
        a3 += __shfl_xor(a3, off, 64);
        a4 += __shfl_xor(a4, off, 64);
        a5 += __shfl_xor(a5, off, 64);
        a6 += __shfl_xor(a6, off, 64);
        a7 += __shfl_xor(a7, off, 64);
    }
    float ss = a0*a0 + a1*a1 + a2*a2 + a3*a3 + a4*a4 + a5*a5 + a6*a6 + a7*a7;
    ss += __shfl_xor(ss, 1, 64);
    ss += __shfl_xor(ss, 2, 64);
    ss += __shfl_xor(ss, 4, 64);
    float scale = 1.0f / fmaxf(sqrtf(ss), 1e-12f);

    if (q == 0) {
        float4* po = reinterpret_cast<float4*>(out + (size_t)node * EMB_D
                                               + (ql << 3));
        po[0] = make_float4(a0 * scale, a1 * scale, a2 * scale, a3 * scale);
        po[1] = make_float4(a4 * scale, a5 * scale, a6 * scale, a7 * scale);
    }
}

// ===========================================================================
// Tier C: atomic scatter fallback.
// ===========================================================================
__global__ void lightgcn_scatter(const float* __restrict__ emb,
                                 const float* __restrict__ w,
                                 const int* __restrict__ src,
                                 const int* __restrict__ dst,
                                 float* __restrict__ h, int E) {
    long long t = (long long)blockIdx.x * blockDim.x + threadIdx.x;
    int e = (int)(t >> 4);
    int d = (int)(t & 15) << 2;
    if (e >= E) return;
    int s = src[e]; int v = dst[e]; float wt = w[e];
    const float4 m = *reinterpret_cast<const float4*>(emb + (size_t)s * EMB_D + d);
    float* o = h + (size_t)v * EMB_D + d;
    unsafeAtomicAdd(o + 0, m.x * wt);
    unsafeAtomicAdd(o + 1, m.y * wt);
    unsafeAtomicAdd(o + 2, m.z * wt);
    unsafeAtomicAdd(o + 3, m.w * wt);
}

__global__ void lightgcn_normalize(float* __restrict__ h, int N) {
    int row = blockIdx.x * (blockDim.x >> 6) + (threadIdx.x >> 6);
    int lane = threadIdx.x & 63;
    if (row >= N) return;
    float x = h[(size_t)row * EMB_D + lane];
    float ss = x * x;
    #pragma unroll
    for (int off = 32; off > 0; off >>= 1)
        ss += __shfl_xor(ss, off, 64);
    h[(size_t)row * EMB_D + lane] = x / fmaxf(sqrtf(ss), 1e-12f);
}

extern "C" void kernel_launch(void* const* d_in, const int* in_sizes, int n_in,
                              void* d_out, int out_size, void* d_ws, size_t ws_size,
                              hipStream_t stream) {
    const float* emb = (const float*)d_in[0];   // [N, 64] fp32
    const float* w   = (const float*)d_in[1];   // [E] fp32
    const int*   src = (const int*)d_in[2];     // [E] int32
    const int*   dst = (const int*)d_in[3];     // [E] int32
    float* out = (float*)d_out;

    const int N = in_sizes[0] / EMB_D;
    const int E = in_sizes[1];
    const int block = 256;
    const int G = (N + SPAN - 1) / SPAN;

    const int M3 = G * NCHUNK2;
    const int numB3 = (M3 + SB - 1) / SB;
    const int chunk3 = (E + NCHUNK2 - 1) / NCHUNK2;

    // ---- Tier A6 workspace: cntT[M3] | scanT[M3+1] | partial | blockoff |
    //      pad | stream8[E] uint2 | pad | emb16  (~27.4 MB) ----
    size_t intsA5 = (size_t)M3 + (size_t)(M3 + 1) + 2 * (size_t)numB3;
    size_t strOff5 = (intsA5 * sizeof(int) + 15) & ~(size_t)15;
    size_t embOff5 = (strOff5 + (size_t)E * sizeof(uint2) + 15) & ~(size_t)15;
    size_t neededA5 = embOff5 + (size_t)N * EMB_D * sizeof(__half);

    // ---- Tier A3 workspace (~35.7 MB) ----
    size_t intsA3 = (size_t)M3 + (size_t)(M3 + 1) + 2 * (size_t)numB3
                  + (size_t)(N + 1);
    size_t strOff = (intsA3 * sizeof(int) + 15) & ~(size_t)15;
    size_t pkdOff = strOff + (size_t)E * sizeof(uint2);
    size_t embOff3 = (pkdOff + (size_t)E * sizeof(unsigned int) + 15)
                     & ~(size_t)15;
    size_t neededA3 = embOff3 + (size_t)N * EMB_D * sizeof(__half);

    if (ws_size >= neededA5 && G <= MAXG && chunk3 <= CHMAX &&
        E < (1 << 28) && N < (1 << 17)) {
        int* cntT     = (int*)d_ws;              // M3
        int* scanT    = cntT + M3;               // M3+1
        int* partial  = scanT + M3 + 1;          // numB3
        int* blockoff = partial + numB3;         // numB3
        uint2* stream8 = (uint2*)((char*)d_ws + strOff5);   // E
        __half2* emb16 = (__half2*)((char*)d_ws + embOff5);

        int n2 = N * (EMB_D / 2);

        a1_cast_hist<<<CAST_BLOCKS + NCHUNK2, block, 0, stream>>>(
            (const float2*)emb, emb16, n2, dst, cntT, E, G, chunk3);

        scan_reduceB<<<numB3, SB, 0, stream>>>(cntT, partial, M3);
        scan_partials<<<1, SB, 0, stream>>>(partial, blockoff, scanT, numB3, M3);
        scan_applyB<<<numB3, SB, 0, stream>>>(cntT, blockoff, scanT, M3);

        partition_sort<<<NCHUNK2, 512, 0, stream>>>(src, dst, w, cntT, scanT,
                                                    stream8, E, G, chunk3);

        gather_fused<<<G, 512, 0, stream>>>((const char*)emb16, stream8,
                                            scanT, out, N);
    } else if (ws_size >= neededA3 && G <= MAXG && chunk3 <= CHMAX &&
               E < (1 << 28) && N < (1 << 17)) {
        int* cntT     = (int*)d_ws;              // M3
        int* scanT    = cntT + M3;               // M3+1
        int* partial  = scanT + M3 + 1;          // numB3
        int* blockoff = partial + numB3;         // numB3
        int* offsets  = blockoff + numB3;        // N+1
        uint2* stream8 = (uint2*)((char*)d_ws + strOff);                // E
        unsigned int* packed = (unsigned int*)((char*)d_ws + pkdOff);   // E
        __half2* emb16 = (__half2*)((char*)d_ws + embOff3);

        int n2 = N * (EMB_D / 2);

        a1_cast_hist<<<CAST_BLOCKS + NCHUNK2, block, 0, stream>>>(
            (const float2*)emb, emb16, n2, dst, cntT, E, G, chunk3);

        scan_reduceB<<<numB3, SB, 0, stream>>>(cntT, partial, M3);
        scan_partials<<<1, SB, 0, stream>>>(partial, blockoff, scanT, numB3, M3);
        scan_applyB<<<numB3, SB, 0, stream>>>(cntT, blockoff, scanT, M3);

        partition_sort<<<NCHUNK2, 512, 0, stream>>>(src, dst, w, cntT, scanT,
                                                    stream8, E, G, chunk3);
        group_csr2<<<G, block, 0, stream>>>(stream8, scanT, packed, offsets,
                                            N, E);

        int gridN = (N + 3) / 4;
        gatherV_kernel<<<gridN, 256, 0, stream>>>((const char*)emb16, offsets,
                                                  packed, out, N);
    } else {
        hipMemsetAsync(d_out, 0, (size_t)out_size * sizeof(float), stream);
        long long total = (long long)E * 16;
        int grid = (int)((total + block - 1) / block);
        lightgcn_scatter<<<grid, block, 0, stream>>>(emb, w, src, dst, out, E);
        int gridN = (N + 3) / 4;
        lightgcn_normalize<<<gridN, 256, 0, stream>>>(out, N);
    }
}